// Round 1
// baseline (197.735 us; speedup 1.0000x reference)
//
#include <hip/hip_runtime.h>

namespace {
constexpr int S = 1024, I = 512, C = 8, H = 8;
constexpr float LNEPS = 1e-5f;
constexpr float SCALE = 0.35355339059327373f; // 8^-0.5
}

// Load one (s,i) row of m (8 consecutive floats) and LayerNorm it.
__device__ __forceinline__ void load_ln(const float4* __restrict__ m4, int row,
                                        const float gm[C], const float bt[C],
                                        float x[C]) {
    float4 a = m4[row * 2], b = m4[row * 2 + 1];
    x[0] = a.x; x[1] = a.y; x[2] = a.z; x[3] = a.w;
    x[4] = b.x; x[5] = b.y; x[6] = b.z; x[7] = b.w;
    float mu = 0.f;
#pragma unroll
    for (int c = 0; c < C; c++) mu += x[c];
    mu *= 0.125f;
    float var = 0.f;
#pragma unroll
    for (int c = 0; c < C; c++) { float d = x[c] - mu; var += d * d; }
    var *= 0.125f;
    float inv = rsqrtf(var + LNEPS);
#pragma unroll
    for (int c = 0; c < C; c++) x[c] = (x[c] - mu) * inv * gm[c] + bt[c];
}

// K1: xbar_sum[i,c] = sum over s of LN(m[s,i,:])[c]   (divide by S later)
__global__ __launch_bounds__(256) void k1_xbar(const float* __restrict__ m,
                                               const float* __restrict__ gamma,
                                               const float* __restrict__ beta,
                                               float* __restrict__ xbar_sum) {
    int g = blockIdx.x * 256 + threadIdx.x;  // I*32 threads
    int i = g & (I - 1);
    int s0 = g >> 9;  // [0,32)
    float gm[C], bt[C];
#pragma unroll
    for (int c = 0; c < C; c++) { gm[c] = gamma[c]; bt[c] = beta[c]; }
    float acc[C];
#pragma unroll
    for (int c = 0; c < C; c++) acc[c] = 0.f;
    const float4* m4 = (const float4*)m;
    for (int s = s0; s < S; s += 32) {
        float x[C];
        load_ln(m4, s * I + i, gm, bt, x);
#pragma unroll
        for (int c = 0; c < C; c++) acc[c] += x[c];
    }
#pragma unroll
    for (int c = 0; c < C; c++) atomicAdd(&xbar_sum[i * C + c], acc[c]);
}

// K1b: q[i, j=h*8+c] = (xbar_sum[i,:]/S) . Wq[j,:]
__global__ __launch_bounds__(256) void k1b_q(const float* __restrict__ xbar_sum,
                                             const float* __restrict__ Wq,
                                             float* __restrict__ q) {
    int g = blockIdx.x * 256 + threadIdx.x;  // I*64 threads
    int i = g >> 6, j = g & 63;
    float acc = 0.f;
#pragma unroll
    for (int c = 0; c < C; c++) acc += xbar_sum[i * C + c] * Wq[j * C + c];
    q[g] = acc * (1.0f / S);
}

// K2: denom[i,h] = sum over s of exp(SCALE * q[i,h,:] . k[s,i,:])
__global__ __launch_bounds__(256) void k2_denom(const float* __restrict__ m,
                                                const float* __restrict__ gamma,
                                                const float* __restrict__ beta,
                                                const float* __restrict__ Wk,
                                                const float* __restrict__ q,
                                                float* __restrict__ denom) {
    int g = blockIdx.x * 256 + threadIdx.x;  // I*128 threads
    int i = g & (I - 1);
    int s0 = g >> 9;  // [0,128)
    float gm[C], bt[C];
#pragma unroll
    for (int c = 0; c < C; c++) { gm[c] = gamma[c]; bt[c] = beta[c]; }
    float qq[H][C];
#pragma unroll
    for (int h = 0; h < H; h++)
#pragma unroll
        for (int c = 0; c < C; c++) qq[h][c] = q[i * 64 + h * C + c];
    float acc[H];
#pragma unroll
    for (int h = 0; h < H; h++) acc[h] = 0.f;
    const float4* m4 = (const float4*)m;
    for (int s = s0; s < S; s += 128) {
        float x[C];
        load_ln(m4, s * I + i, gm, bt, x);
        float k[C];
#pragma unroll
        for (int c = 0; c < C; c++) {
            float a = 0.f;
#pragma unroll
            for (int c2 = 0; c2 < C; c2++) a += x[c2] * Wk[c * C + c2];
            k[c] = a;
        }
#pragma unroll
        for (int h = 0; h < H; h++) {
            float l = 0.f;
#pragma unroll
            for (int c = 0; c < C; c++) l += qq[h][c] * k[c];
            acc[h] += __expf(l * SCALE);
        }
    }
#pragma unroll
    for (int h = 0; h < H; h++) atomicAdd(&denom[i * H + h], acc[h]);
}

// K3: final output per row (s,i)
__global__ __launch_bounds__(256) void k3_out(const float* __restrict__ m,
                                              const float* __restrict__ gamma,
                                              const float* __restrict__ beta,
                                              const float* __restrict__ Wk,
                                              const float* __restrict__ Wv,
                                              const float* __restrict__ Wg,
                                              const float* __restrict__ Wo,
                                              const float* __restrict__ bo,
                                              const float* __restrict__ q,
                                              const float* __restrict__ denom,
                                              float* __restrict__ out) {
    int g = blockIdx.x * 256 + threadIdx.x;  // I*(S/4) threads
    int i = g & (I - 1);
    int s0 = g >> 9;  // [0,256)
    float gm[C], bt[C];
#pragma unroll
    for (int c = 0; c < C; c++) { gm[c] = gamma[c]; bt[c] = beta[c]; }
    float qq[H][C];
#pragma unroll
    for (int h = 0; h < H; h++)
#pragma unroll
        for (int c = 0; c < C; c++) qq[h][c] = q[i * 64 + h * C + c];
    float rden[H];
#pragma unroll
    for (int h = 0; h < H; h++) rden[h] = 1.0f / denom[i * H + h];
    const float4* m4 = (const float4*)m;
    float4* out4 = (float4*)out;
    for (int s = s0; s < S; s += S / 4) {
        int row = s * I + i;
        float x[C];
        load_ln(m4, row, gm, bt, x);
        float k[C], v[C];
#pragma unroll
        for (int c = 0; c < C; c++) {
            float ak = 0.f, av = 0.f;
#pragma unroll
            for (int c2 = 0; c2 < C; c2++) {
                ak += x[c2] * Wk[c * C + c2];
                av += x[c2] * Wv[c * C + c2];
            }
            k[c] = ak; v[c] = av;
        }
        float oacc[C];
#pragma unroll
        for (int c = 0; c < C; c++) oacc[c] = bo[c];
#pragma unroll
        for (int h = 0; h < H; h++) {
            float l = 0.f;
#pragma unroll
            for (int c = 0; c < C; c++) l += qq[h][c] * k[c];
            float ah = __expf(l * SCALE) * rden[h];
#pragma unroll
            for (int c = 0; c < C; c++) {
                float z = 0.f;
#pragma unroll
                for (int c2 = 0; c2 < C; c2++) z += x[c2] * Wg[(h * C + c) * C + c2];
                float gate = __builtin_amdgcn_rcpf(1.0f + __expf(-z));
                float o = gate * ah * v[c];
#pragma unroll
                for (int c2 = 0; c2 < C; c2++) oacc[c2] += o * Wo[c2 * 64 + h * C + c];
            }
        }
        float4 r0 = {oacc[0], oacc[1], oacc[2], oacc[3]};
        float4 r1 = {oacc[4], oacc[5], oacc[6], oacc[7]};
        out4[row * 2] = r0;
        out4[row * 2 + 1] = r1;
    }
}

extern "C" void kernel_launch(void* const* d_in, const int* in_sizes, int n_in,
                              void* d_out, int out_size, void* d_ws, size_t ws_size,
                              hipStream_t stream) {
    const float* m     = (const float*)d_in[0];
    const float* gamma = (const float*)d_in[1];
    const float* beta  = (const float*)d_in[2];
    const float* Wq    = (const float*)d_in[3];
    const float* Wk    = (const float*)d_in[4];
    const float* Wv    = (const float*)d_in[5];
    const float* Wg    = (const float*)d_in[6];
    const float* Wo    = (const float*)d_in[7];
    const float* bo    = (const float*)d_in[8];
    float* out = (float*)d_out;

    float* ws    = (float*)d_ws;
    float* xbar  = ws;                    // I*C   = 4096 floats
    float* denom = ws + I * C;            // I*H   = 4096 floats
    float* q     = ws + I * C + I * H;    // I*H*C = 32768 floats

    // zero the atomic accumulators (ws is poisoned before every launch)
    hipMemsetAsync(d_ws, 0, (size_t)(I * C + I * H) * sizeof(float), stream);

    k1_xbar<<<I * 32 / 256, 256, 0, stream>>>(m, gamma, beta, xbar);
    k1b_q<<<I * H * C / 256, 256, 0, stream>>>(xbar, Wq, q);
    k2_denom<<<I * 128 / 256, 256, 0, stream>>>(m, gamma, beta, Wk, q, denom);
    k3_out<<<I * (S / 4) / 256, 256, 0, stream>>>(m, gamma, beta, Wk, Wv, Wg, Wo,
                                                  bo, q, denom, out);
}

// Round 2
// 131.912 us; speedup vs baseline: 1.4990x; 1.4990x over previous
//
#include <hip/hip_runtime.h>

namespace {
constexpr int S = 1024, I = 512, C = 8, H = 8;
constexpr float LNEPS = 1e-5f;
constexpr float SCALE = 0.35355339059327373f; // 8^-0.5
}

__device__ __forceinline__ float dot8(const float x[8], float4 a, float4 b) {
    float r = x[0] * a.x;
    r += x[1] * a.y; r += x[2] * a.z; r += x[3] * a.w;
    r += x[4] * b.x; r += x[5] * b.y; r += x[6] * b.z; r += x[7] * b.w;
    return r;
}

__device__ __forceinline__ void ln8(float4 a, float4 b, const float gm[8],
                                    const float bt[8], float x[8]) {
    x[0] = a.x; x[1] = a.y; x[2] = a.z; x[3] = a.w;
    x[4] = b.x; x[5] = b.y; x[6] = b.z; x[7] = b.w;
    float mu = 0.f;
#pragma unroll
    for (int c = 0; c < 8; c++) mu += x[c];
    mu *= 0.125f;
    float var = 0.f;
#pragma unroll
    for (int c = 0; c < 8; c++) { float d = x[c] - mu; var += d * d; }
    var *= 0.125f;
    float inv = rsqrtf(var + LNEPS);
#pragma unroll
    for (int c = 0; c < 8; c++) x[c] = (x[c] - mu) * inv * gm[c] + bt[c];
}

// K1: partial LN-sums over s-chunks. part1[sc][i][c], sc in [0,CH1)
__global__ __launch_bounds__(256) void k1_part(const float* __restrict__ m,
                                               const float* __restrict__ gamma,
                                               const float* __restrict__ beta,
                                               float* __restrict__ part1, int CH1) {
    int g = blockIdx.x * 256 + threadIdx.x;   // I*CH1 threads
    int i = g & (I - 1);
    int sc = g >> 9;
    int niter = S / CH1;
    float gm[8], bt[8];
#pragma unroll
    for (int c = 0; c < 8; c++) { gm[c] = gamma[c]; bt[c] = beta[c]; }
    float acc[8];
#pragma unroll
    for (int c = 0; c < 8; c++) acc[c] = 0.f;
    const float4* m4 = (const float4*)m;
    for (int j = 0; j < niter; j++) {
        int row = (sc * niter + j) * I + i;
        float x[8];
        ln8(m4[row * 2], m4[row * 2 + 1], gm, bt, x);
#pragma unroll
        for (int c = 0; c < 8; c++) acc[c] += x[c];
    }
    float4* p4 = (float4*)&part1[((size_t)sc * I + i) * 8];
    p4[0] = make_float4(acc[0], acc[1], acc[2], acc[3]);
    p4[1] = make_float4(acc[4], acc[5], acc[6], acc[7]);
}

// K1b: reduce part1 over sc, then qk[i,h,c2] = SCALE/S * sum_c (xbar.Wq_hc) Wk[c,c2]
__global__ __launch_bounds__(64) void k1b_qk(const float* __restrict__ part1,
                                             const float* __restrict__ Wq,
                                             const float* __restrict__ Wk,
                                             float* __restrict__ qk, int CH1) {
    int i = blockIdx.x, t = threadIdx.x;
    float xs[8];
#pragma unroll
    for (int c = 0; c < 8; c++) xs[c] = 0.f;
    const float4* p4 = (const float4*)part1;
    for (int p = t; p < CH1; p += 64) {
        float4 a = p4[((size_t)p * I + i) * 2], b = p4[((size_t)p * I + i) * 2 + 1];
        xs[0] += a.x; xs[1] += a.y; xs[2] += a.z; xs[3] += a.w;
        xs[4] += b.x; xs[5] += b.y; xs[6] += b.z; xs[7] += b.w;
    }
#pragma unroll
    for (int d = 1; d < 64; d <<= 1)
#pragma unroll
        for (int c = 0; c < 8; c++) xs[c] += __shfl_xor(xs[c], d, 64);
    int h = t >> 3, c2 = t & 7;
    float acc = 0.f;
#pragma unroll
    for (int c = 0; c < 8; c++) {
        float qc = 0.f;
#pragma unroll
        for (int c3 = 0; c3 < 8; c3++) qc += xs[c3] * Wq[(h * 8 + c) * 8 + c3];
        acc += qc * Wk[c * 8 + c2];
    }
    qk[i * 64 + t] = acc * (SCALE / 1024.0f);
}

// K2: partial exp-sums. part2[sc][i][h], sc in [0,CH2)
__global__ __launch_bounds__(256) void k2_part(const float* __restrict__ m,
                                               const float* __restrict__ gamma,
                                               const float* __restrict__ beta,
                                               const float* __restrict__ qk,
                                               float* __restrict__ part2, int CH2) {
    int g = blockIdx.x * 256 + threadIdx.x;   // I*CH2 threads
    int i = g & (I - 1);
    int sc = g >> 9;
    int niter = S / CH2;
    float gm[8], bt[8];
#pragma unroll
    for (int c = 0; c < 8; c++) { gm[c] = gamma[c]; bt[c] = beta[c]; }
    const float4* qk4 = (const float4*)qk;
    float4 qv[16];
#pragma unroll
    for (int j = 0; j < 16; j++) qv[j] = qk4[i * 16 + j];
    float acc[8];
#pragma unroll
    for (int h = 0; h < 8; h++) acc[h] = 0.f;
    const float4* m4 = (const float4*)m;
    for (int j0 = 0; j0 < niter; j0 += 4) {
        float x[4][8];
#pragma unroll
        for (int r = 0; r < 4; r++) {
            int row = (sc * niter + j0 + r) * I + i;
            ln8(m4[row * 2], m4[row * 2 + 1], gm, bt, x[r]);
        }
#pragma unroll
        for (int h = 0; h < 8; h++)
#pragma unroll
            for (int r = 0; r < 4; r++)
                acc[h] += __expf(dot8(x[r], qv[h * 2], qv[h * 2 + 1]));
    }
    float4* p4 = (float4*)&part2[((size_t)sc * I + i) * 8];
    p4[0] = make_float4(acc[0], acc[1], acc[2], acc[3]);
    p4[1] = make_float4(acc[4], acc[5], acc[6], acc[7]);
}

// K2b: reduce part2 over sc -> rden[i,h] = 1/denom
__global__ __launch_bounds__(64) void k2b_rden(const float* __restrict__ part2,
                                               float* __restrict__ rden, int CH2) {
    int i = blockIdx.x, t = threadIdx.x;
    float d[8];
#pragma unroll
    for (int c = 0; c < 8; c++) d[c] = 0.f;
    const float4* p4 = (const float4*)part2;
    for (int p = t; p < CH2; p += 64) {
        float4 a = p4[((size_t)p * I + i) * 2], b = p4[((size_t)p * I + i) * 2 + 1];
        d[0] += a.x; d[1] += a.y; d[2] += a.z; d[3] += a.w;
        d[4] += b.x; d[5] += b.y; d[6] += b.z; d[7] += b.w;
    }
#pragma unroll
    for (int dd = 1; dd < 64; dd <<= 1)
#pragma unroll
        for (int c = 0; c < 8; c++) d[c] += __shfl_xor(d[c], dd, 64);
    if (t < 8) rden[i * 8 + t] = 1.0f / d[t];
}

// K3: final output. 4 rows (same i) per thread; weights LDS-resident.
__global__ __launch_bounds__(256) void k3_out(const float* __restrict__ m,
                                              const float* __restrict__ gamma,
                                              const float* __restrict__ beta,
                                              const float* __restrict__ Wv,
                                              const float* __restrict__ Wg,
                                              const float* __restrict__ Wo,
                                              const float* __restrict__ bo,
                                              const float* __restrict__ qk,
                                              const float* __restrict__ rden,
                                              float* __restrict__ out) {
    __shared__ __align__(16) float sWv[64];
    __shared__ __align__(16) float sWg[512];
    __shared__ __align__(16) float sWoT[512];  // sWoT[j][c2] = Wo[c2][j]
    int t = threadIdx.x;
    if (t < 64) sWv[t] = Wv[t];
    sWg[t] = Wg[t];
    sWg[t + 256] = Wg[t + 256];
    {
        int j = t & 63, c2 = t >> 6;
        sWoT[j * 8 + c2] = Wo[c2 * 64 + j];
        sWoT[j * 8 + c2 + 4] = Wo[(c2 + 4) * 64 + j];
    }
    __syncthreads();

    float gm[8], bt[8], bov[8];
#pragma unroll
    for (int c = 0; c < 8; c++) { gm[c] = gamma[c]; bt[c] = beta[c]; bov[c] = bo[c]; }

    int g = blockIdx.x * 256 + t;   // I*256 threads
    int i = g & (I - 1);
    int sg = g >> 9;                // [0,256)
    const float4* m4 = (const float4*)m;
    float4* out4 = (float4*)out;

    float4 xa[4], xb[4];
#pragma unroll
    for (int r = 0; r < 4; r++) {
        int row = (sg + 256 * r) * I + i;
        xa[r] = m4[row * 2]; xb[r] = m4[row * 2 + 1];
    }
    float x[4][8];
#pragma unroll
    for (int r = 0; r < 4; r++) ln8(xa[r], xb[r], gm, bt, x[r]);

    const float4* sWv4 = (const float4*)sWv;
    const float4* sWg4 = (const float4*)sWg;
    const float4* sWoT4 = (const float4*)sWoT;

    float v[4][8];
#pragma unroll
    for (int c = 0; c < 8; c++) {
        float4 w0 = sWv4[c * 2], w1 = sWv4[c * 2 + 1];
#pragma unroll
        for (int r = 0; r < 4; r++) v[r][c] = dot8(x[r], w0, w1);
    }

    float oacc[4][8];
#pragma unroll
    for (int r = 0; r < 4; r++)
#pragma unroll
        for (int c2 = 0; c2 < 8; c2++) oacc[r][c2] = bov[c2];

    const float4* qk4 = (const float4*)qk;
#pragma unroll 1
    for (int h = 0; h < 8; h++) {
        float4 q0 = qk4[i * 16 + h * 2], q1 = qk4[i * 16 + h * 2 + 1];
        float rd = rden[i * 8 + h];
        float a_[4];
#pragma unroll
        for (int r = 0; r < 4; r++) a_[r] = __expf(dot8(x[r], q0, q1)) * rd;
#pragma unroll
        for (int c = 0; c < 8; c++) {
            int hc = h * 8 + c;
            float4 wg0 = sWg4[hc * 2], wg1 = sWg4[hc * 2 + 1];
            float o_[4];
#pragma unroll
            for (int r = 0; r < 4; r++) {
                float z = dot8(x[r], wg0, wg1);
                float gate = __builtin_amdgcn_rcpf(1.0f + __expf(-z));
                o_[r] = gate * a_[r] * v[r][c];
            }
            float4 wo0 = sWoT4[hc * 2], wo1 = sWoT4[hc * 2 + 1];
#pragma unroll
            for (int r = 0; r < 4; r++) {
                oacc[r][0] += o_[r] * wo0.x; oacc[r][1] += o_[r] * wo0.y;
                oacc[r][2] += o_[r] * wo0.z; oacc[r][3] += o_[r] * wo0.w;
                oacc[r][4] += o_[r] * wo1.x; oacc[r][5] += o_[r] * wo1.y;
                oacc[r][6] += o_[r] * wo1.z; oacc[r][7] += o_[r] * wo1.w;
            }
        }
    }
#pragma unroll
    for (int r = 0; r < 4; r++) {
        int row = (sg + 256 * r) * I + i;
        out4[row * 2] = make_float4(oacc[r][0], oacc[r][1], oacc[r][2], oacc[r][3]);
        out4[row * 2 + 1] = make_float4(oacc[r][4], oacc[r][5], oacc[r][6], oacc[r][7]);
    }
}

extern "C" void kernel_launch(void* const* d_in, const int* in_sizes, int n_in,
                              void* d_out, int out_size, void* d_ws, size_t ws_size,
                              hipStream_t stream) {
    const float* m     = (const float*)d_in[0];
    const float* gamma = (const float*)d_in[1];
    const float* beta  = (const float*)d_in[2];
    const float* Wq    = (const float*)d_in[3];
    const float* Wk    = (const float*)d_in[4];
    const float* Wv    = (const float*)d_in[5];
    const float* Wg    = (const float*)d_in[6];
    const float* Wo    = (const float*)d_in[7];
    const float* bo    = (const float*)d_in[8];
    float* out = (float*)d_out;

    const size_t small = (size_t)I * 64 * 4 + (size_t)I * 8 * 4; // qk + rden
    int CH1 = 256, CH2 = 256;
    auto need = [&](int c1, int c2) {
        return ((size_t)(c1 + c2) * I * C * 4) + small;
    };
    if (need(256, 256) > ws_size) { CH1 = CH2 = 64; }
    if (need(CH1, CH2) > ws_size) { CH1 = CH2 = 16; }

    float* ws    = (float*)d_ws;
    float* part1 = ws;
    float* part2 = part1 + (size_t)CH1 * I * C;
    float* qk    = part2 + (size_t)CH2 * I * C;
    float* rden  = qk + (size_t)I * 64;

    k1_part<<<I * CH1 / 256, 256, 0, stream>>>(m, gamma, beta, part1, CH1);
    k1b_qk<<<I, 64, 0, stream>>>(part1, Wq, Wk, qk, CH1);
    k2_part<<<I * CH2 / 256, 256, 0, stream>>>(m, gamma, beta, qk, part2, CH2);
    k2b_rden<<<I, 64, 0, stream>>>(part2, rden, CH2);
    k3_out<<<I * 256 / 256, 256, 0, stream>>>(m, gamma, beta, Wv, Wg, Wo, bo, qk,
                                              rden, out);
}